// Round 1
// baseline (182.611 us; speedup 1.0000x reference)
//
#include <hip/hip_runtime.h>
#include <hip/hip_bf16.h>

typedef unsigned int u32;
typedef unsigned short u16;
typedef __attribute__((ext_vector_type(4))) short bf16x4;
typedef __attribute__((ext_vector_type(8))) short bf16x8;
typedef __attribute__((ext_vector_type(4))) float f32x4;

typedef __attribute__((address_space(1))) const u32 gu32;
typedef __attribute__((address_space(3))) u32 lu32;

#define MFMA(a,b,c) __builtin_amdgcn_mfma_f32_16x16x32_bf16((a),(b),(c),0,0,0)

// ---- problem constants ----
// B=131072, D=64, DEPTH=10, C=16, N_INNER=1023, N_LEAF=1024
static constexpr int NCH = 17;   // chunk 0 = prefix (levels 0..3, 15 nodes), chunks 1..16 = subtrees (63 nodes)

// ---- workspace layout (bytes) ----
static constexpr size_t WS_WFRAG = 0;        // u16 [17][4][2][2][64][8] = 278528 B  (ch, ct, kt, hi/lo, lane, 8)
static constexpr size_t WS_QFRAG = 278528;   // u16 [16][2][2][64][8]   = 65536 B   (s, kt, hi/lo, lane, 8)
static constexpr size_t WS_BTAB  = 344064;   // f32 [17][64] = 4352 (padded to 4608)
static constexpr size_t WS_ETAB  = 348672;   // f32 [17][64]
static constexpr size_t WS_NEED  = 353024;

__device__ __forceinline__ u16 f2bf(float f){       // fp32 -> bf16 RNE
  u32 u = __float_as_uint(f);
  return (u16)((u + 0x7fffu + ((u >> 16) & 1u)) >> 16);
}
__device__ __forceinline__ float bf2f(u16 h){ return __uint_as_float(((u32)h) << 16); }

// map (chunk, local col) -> global node index in reference W order, or -1 (zero pad)
__device__ __forceinline__ int nodemap(int ch, int n){
  if (ch == 0) return (n < 15) ? n : -1;            // prefix: global nodes 0..14
  if (n >= 63) return -1;
  int v = n + 1;
  int L = 31 - __clz(v);                            // local level 0..5  (tree depth L+4)
  return ((1 << (L + 4)) - 1) + ((ch - 1) << L) + (v - (1 << L));
}

// =====================  prep: pack W/Q fragments + b/beta tables  =====================
__global__ void sdt_prep(const float* __restrict__ W, const float* __restrict__ b,
                         const float* __restrict__ beta, const float* __restrict__ LP,
                         char* __restrict__ ws)
{
  const int bid = blockIdx.x, t = threadIdx.x;
  u16* wfrag = (u16*)(ws + WS_WFRAG);
  u16* qfrag = (u16*)(ws + WS_QFRAG);
  float* bt  = (float*)(ws + WS_BTAB);
  float* et  = (float*)(ws + WS_ETAB);

  if (bid < 34){                                    // W fragments: [17][4][2][64] threads
    int id = bid*256 + t;
    if (id < 17*4*2*64){
      int lane = id & 63, kt = (id >> 6) & 1, ct = (id >> 7) & 3, ch = id >> 9;
      int n = ct*16 + (lane & 15);
      int g = nodemap(ch, n);
      int k0 = kt*32 + ((lane >> 4) << 3);
      size_t basH = ((((size_t)ch*4 + ct)*2 + kt)*2 + 0)*512 + (size_t)lane*8;
      size_t basL = basH + 512;
      #pragma unroll
      for (int j = 0; j < 8; ++j){
        float v = (g >= 0) ? W[(size_t)g*64 + k0 + j] : 0.0f;
        u16 h = f2bf(v);
        wfrag[basH + j] = h;
        wfrag[basL + j] = f2bf(v - bf2f(h));
      }
    }
  } else if (bid < 42){                             // Q fragments: [16][2][64] threads
    int id = (bid - 34)*256 + t;
    int lane = id & 63, kt = (id >> 6) & 1, s = id >> 7;
    int c = lane & 15;
    size_t basH = (((size_t)s*2 + kt)*2 + 0)*512 + (size_t)lane*8;
    size_t basL = basH + 512;
    #pragma unroll
    for (int j = 0; j < 8; ++j){
      int leaf = s*64 + kt*32 + ((lane >> 4) << 3) + j;
      const float* row = LP + (size_t)leaf*16;
      float m = row[0];
      #pragma unroll
      for (int cc = 1; cc < 16; ++cc) m = fmaxf(m, row[cc]);
      float ssum = 0.f;
      #pragma unroll
      for (int cc = 0; cc < 16; ++cc) ssum += __expf(row[cc] - m);
      float q = __expf(row[c] - m) / ssum;
      u16 h = f2bf(q);
      qfrag[basH + j] = h;
      qfrag[basL + j] = f2bf(q - bf2f(h));
    }
  } else {                                          // b/beta reordered tables
    int id = (bid - 42)*256 + t;
    if (id < 17*64){
      int n = id & 63, ch = id >> 6;
      int g = nodemap(ch, n);
      bt[id] = (g >= 0) ? b[g]    : 0.0f;
      et[id] = (g >= 0) ? beta[g] : 0.0f;
    }
  }
}

// =====================  main fused kernel  =====================
// grid 2048 x 256 threads; block handles 64 rows; wave w owns rows w*16..w*16+15
__global__ __launch_bounds__(256, 2) void sdt_main(
    const float* __restrict__ X, const char* __restrict__ ws,
    float* __restrict__ out)
{
  __shared__ u16   sXh[64*64];        // X hi, bf16, XOR-swizzled rows      (8 KB)
  __shared__ u16   sXl[64*64];        // X lo                               (8 KB)
  __shared__ float sP[4][16*68];      // per-wave sigmoid slice, pad 68     (17 KB)
  __shared__ u16   sLpH[4][16*64];    // per-wave leaf-path hi, swizzled    (8 KB)
  __shared__ u16   sLpL[4][16*64];    // per-wave leaf-path lo              (8 KB)
  __shared__ float sPath[4][16*17];   // per-wave level-4 prefix probs      (4.25 KB)
  __shared__ u16   sWf[4*2*2*64*8];   // staged W frag chunk                (16 KB)
  __shared__ u16   sQf[2*2*64*8];     // staged Q frag chunk                (4 KB)

  const int tid  = threadIdx.x;
  const int w    = tid >> 6;
  const int lane = tid & 63;
  const int bid  = blockIdx.x;

  const u16*   wfrag = (const u16*)(ws + WS_WFRAG);
  const u16*   qfrag = (const u16*)(ws + WS_QFRAG);
  const float* bTab  = (const float*)(ws + WS_BTAB);
  const float* eTab  = (const float*)(ws + WS_ETAB);

  // ---- stage X tile (64x64 fp32 -> bf16 hi/lo, swizzled) ----
  {
    const float4* Xg = (const float4*)X + (size_t)bid * 1024;
    #pragma unroll
    for (int i = 0; i < 4; ++i){
      int f = tid + i*256;
      float4 v = Xg[f];
      int row = f >> 4;
      int byteo = row*128 + (f & 15)*8;
      int swz = (row & 7) << 4;
      u16 h0 = f2bf(v.x), h1 = f2bf(v.y), h2 = f2bf(v.z), h3 = f2bf(v.w);
      bf16x4 hv = {(short)h0, (short)h1, (short)h2, (short)h3};
      bf16x4 lv = {(short)f2bf(v.x - bf2f(h0)), (short)f2bf(v.y - bf2f(h1)),
                   (short)f2bf(v.z - bf2f(h2)), (short)f2bf(v.w - bf2f(h3))};
      *(bf16x4*)((char*)sXh + (byteo ^ swz)) = hv;
      *(bf16x4*)((char*)sXl + (byteo ^ swz)) = lv;
    }
  }
  // stage W chunk 0 (prefix only uses ct=0 -> 4 segs, one per wave)
  __builtin_amdgcn_global_load_lds((gu32*)((const char*)wfrag + w*1024 + lane*16),
                                   (lu32*)(&sWf[w*512]), 16, 0, 0);
  __syncthreads();

  // persistent X A-fragments for this wave's 16 rows (k-invariant across chunks)
  const int mA   = lane & 15;
  const int kofs = (lane >> 4) * 16;          // byte offset of 8-element k-block
  const int swzA = (mA & 7) << 4;
  const int rowb = (w*16 + mA) * 128;
  const bf16x8 aH0 = *(const bf16x8*)((const char*)sXh + ((rowb + kofs     ) ^ swzA));
  const bf16x8 aH1 = *(const bf16x8*)((const char*)sXh + ((rowb + 64 + kofs) ^ swzA));
  const bf16x8 aL0 = *(const bf16x8*)((const char*)sXl + ((rowb + kofs     ) ^ swzA));
  const bf16x8 aL1 = *(const bf16x8*)((const char*)sXl + ((rowb + 64 + kofs) ^ swzA));

  f32x4 accO = {0.f, 0.f, 0.f, 0.f};          // out tile [16 rows][16 ch], accumulated over chunks
  const int mrow = lane >> 2;                 // 0..15 mixing row
  const int q4   = lane & 3;                  // leaf quarter (16 leaves each)
  float* Pw    = sP[w];
  float* pathw = sPath[w];

  for (int ch = 0; ch < NCH; ++ch){
    // ---- z = X@W'^T (split bf16, 3 products) ; p = sigmoid(beta*(z+b)) -> LDS ----
    const int ncts = (ch == 0) ? 1 : 4;
    for (int ct = 0; ct < ncts; ++ct){
      const bf16x8 wH0 = *(const bf16x8*)(&sWf[((ct*2+0)*2+0)*512 + lane*8]);
      const bf16x8 wL0 = *(const bf16x8*)(&sWf[((ct*2+0)*2+1)*512 + lane*8]);
      const bf16x8 wH1 = *(const bf16x8*)(&sWf[((ct*2+1)*2+0)*512 + lane*8]);
      const bf16x8 wL1 = *(const bf16x8*)(&sWf[((ct*2+1)*2+1)*512 + lane*8]);
      f32x4 az = {0.f, 0.f, 0.f, 0.f};
      az = MFMA(aH0, wH0, az);
      az = MFMA(aH1, wH1, az);
      az = MFMA(aH0, wL0, az);
      az = MFMA(aH1, wL1, az);
      az = MFMA(aL0, wH0, az);
      az = MFMA(aL1, wH1, az);
      const int n = ct*16 + (lane & 15);
      const float bb = bTab[ch*64 + n];
      const float be = eTab[ch*64 + n];
      #pragma unroll
      for (int r = 0; r < 4; ++r){
        const int m = (lane >> 4)*4 + r;
        const float tt = be * (az[r] + bb);
        Pw[m*68 + n] = __fdividef(1.0f, 1.0f + __expf(-tt));
      }
    }
    // ---- per-sample tree mixing (wave-private LDS; no barrier needed) ----
    if (ch == 0){
      // prefix path to the 16 level-4 subtrees
      #pragma unroll
      for (int u = 0; u < 4; ++u){
        const int t = q4*4 + u;
        const float* Pr = &Pw[mrow*68];
        float p0 = Pr[0], p1 = Pr[1 + (t>>3)], p2 = Pr[3 + (t>>2)], p3 = Pr[7 + (t>>1)];
        float f0 = (t & 8) ? p0 : 1.f - p0;
        float f1 = (t & 4) ? p1 : 1.f - p1;
        float f2 = (t & 2) ? p2 : 1.f - p2;
        float f3 = (t & 1) ? p3 : 1.f - p3;
        pathw[mrow*17 + t] = f0*f1*f2*f3;
      }
    } else {
      const int s = ch - 1;
      const float pf = pathw[mrow*17 + s];
      const float* Pr = &Pw[mrow*68];
      const float pA = Pr[0];
      const float pB = Pr[1 + (q4 >> 1)];
      const float pC = Pr[3 + q4];
      const float lpre = pf * ((q4 & 2) ? pA : 1.f - pA) * ((q4 & 1) ? pB : 1.f - pB);
      float a2[2], a3[4], a4[8], a5[16];
      a2[0] = lpre * (1.f - pC); a2[1] = lpre * pC;
      #pragma unroll
      for (int i = 0; i < 2; ++i){
        float p = Pr[7 + 2*q4 + i];
        a3[2*i] = a2[i]*(1.f - p); a3[2*i+1] = a2[i]*p;
      }
      #pragma unroll
      for (int i = 0; i < 4; ++i){
        float p = Pr[15 + 4*q4 + i];
        a4[2*i] = a3[i]*(1.f - p); a4[2*i+1] = a3[i]*p;
      }
      #pragma unroll
      for (int i = 0; i < 8; ++i){
        float p = Pr[31 + 8*q4 + i];
        a5[2*i] = a4[i]*(1.f - p); a5[2*i+1] = a4[i]*p;
      }
      // split leaf-path probs to bf16 hi/lo and store A-fragments
      bf16x8 h0, h1, l0, l1;
      #pragma unroll
      for (int i = 0; i < 8; ++i){
        u16 h = f2bf(a5[i]);   h0[i] = (short)h; l0[i] = (short)f2bf(a5[i]   - bf2f(h));
      }
      #pragma unroll
      for (int i = 0; i < 8; ++i){
        u16 h = f2bf(a5[8+i]); h1[i] = (short)h; l1[i] = (short)f2bf(a5[8+i] - bf2f(h));
      }
      const int bo = mrow*128 + q4*32;
      const int sw = (mrow & 7) << 4;
      *(bf16x8*)((char*)sLpH[w] + ((bo     ) ^ sw)) = h0;
      *(bf16x8*)((char*)sLpH[w] + ((bo + 16) ^ sw)) = h1;
      *(bf16x8*)((char*)sLpL[w] + ((bo     ) ^ sw)) = l0;
      *(bf16x8*)((char*)sLpL[w] + ((bo + 16) ^ sw)) = l1;
      // out += lp @ Q_s   (3-product split: lpH*Qh, lpL*Qh, lpH*Ql)
      const int lb = mA*128 + kofs;
      const bf16x8 pH0 = *(const bf16x8*)((const char*)sLpH[w] + ((lb     ) ^ swzA));
      const bf16x8 pH1 = *(const bf16x8*)((const char*)sLpH[w] + ((lb + 64) ^ swzA));
      const bf16x8 pL0 = *(const bf16x8*)((const char*)sLpL[w] + ((lb     ) ^ swzA));
      const bf16x8 pL1 = *(const bf16x8*)((const char*)sLpL[w] + ((lb + 64) ^ swzA));
      const bf16x8 qH0 = *(const bf16x8*)(&sQf[(0*64 + lane)*8]);
      const bf16x8 qL0 = *(const bf16x8*)(&sQf[(1*64 + lane)*8]);
      const bf16x8 qH1 = *(const bf16x8*)(&sQf[(2*64 + lane)*8]);
      const bf16x8 qL1 = *(const bf16x8*)(&sQf[(3*64 + lane)*8]);
      accO = MFMA(pH0, qH0, accO);
      accO = MFMA(pH1, qH1, accO);
      accO = MFMA(pL0, qH0, accO);
      accO = MFMA(pL1, qH1, accO);
      accO = MFMA(pH0, qL0, accO);
      accO = MFMA(pH1, qL1, accO);
    }
    __syncthreads();                             // all waves done with sWf/sQf
    if (ch < 16){
      const char* wsrc = (const char*)wfrag + (size_t)(ch + 1) * 16384;
      #pragma unroll
      for (int t = 0; t < 4; ++t){
        const int seg = w + 4*t;                 // 16 segs of 1 KB
        __builtin_amdgcn_global_load_lds((gu32*)(wsrc + seg*1024 + lane*16),
                                         (lu32*)(&sWf[seg*512]), 16, 0, 0);
      }
      const char* qsrc = (const char*)qfrag + (size_t)ch * 4096;
      __builtin_amdgcn_global_load_lds((gu32*)(qsrc + w*1024 + lane*16),
                                       (lu32*)(&sQf[w*512]), 16, 0, 0);
      __syncthreads();                           // staged data landed (vmcnt drained)
    }
  }

  // ---- epilogue: rows bid*64 + w*16 + m, cols lane&15 ----
  const size_t ob = ((size_t)bid*64 + w*16) * 16 + (lane & 15);
  #pragma unroll
  for (int r = 0; r < 4; ++r){
    const int m = (lane >> 4)*4 + r;
    out[ob + (size_t)m*16] = accO[r];
  }
}

extern "C" void kernel_launch(void* const* d_in, const int* in_sizes, int n_in,
                              void* d_out, int out_size, void* d_ws, size_t ws_size,
                              hipStream_t stream)
{
  const float* X    = (const float*)d_in[0];
  const float* W    = (const float*)d_in[1];
  const float* b    = (const float*)d_in[2];
  const float* beta = (const float*)d_in[3];
  const float* LP   = (const float*)d_in[4];
  float* out = (float*)d_out;
  char*  ws  = (char*)d_ws;

  if (ws_size < WS_NEED) return;   // leaves d_out poisoned -> loud failure instead of UB

  sdt_prep<<<47, 256, 0, stream>>>(W, b, beta, LP, ws);
  sdt_main<<<2048, 256, 0, stream>>>(X, ws, out);
}

// Round 2
// 121.663 us; speedup vs baseline: 1.5010x; 1.5010x over previous
//
#include <hip/hip_runtime.h>
#include <hip/hip_bf16.h>

typedef unsigned int u32;
typedef unsigned short u16;
typedef __attribute__((ext_vector_type(4))) short bf16x4;
typedef __attribute__((ext_vector_type(8))) short bf16x8;
typedef __attribute__((ext_vector_type(4))) float f32x4;
typedef __attribute__((ext_vector_type(4))) u32 u32x4;

#define MFMA(a,b,c) __builtin_amdgcn_mfma_f32_16x16x32_bf16((a),(b),(c),0,0,0)

// ---- problem constants ----
// B=131072, D=64, DEPTH=10, C=16, N_INNER=1023, N_LEAF=1024
static constexpr int NCH = 17;   // chunk 0 = prefix (levels 0..3, 15 nodes), chunks 1..16 = subtrees (63 nodes)

// ---- workspace layout (bytes) ----
static constexpr size_t WS_WFRAG = 0;        // u16 [17][4][2][2][64][8] = 278528 B  (ch, ct, kt, hi/lo, lane, 8)
static constexpr size_t WS_QFRAG = 278528;   // u16 [16][2][2][64][8]   = 65536 B   (s, kt, hi/lo, lane, 8)
static constexpr size_t WS_EBTAB = 344064;   // float2 [17][64] = 8704 B  (.x = -beta, .y = -beta*b)
static constexpr size_t WS_NEED  = 353024;

__device__ __forceinline__ u16 f2bf(float f){       // fp32 -> bf16 RNE
  u32 u = __float_as_uint(f);
  return (u16)((u + 0x7fffu + ((u >> 16) & 1u)) >> 16);
}
__device__ __forceinline__ float bf2f(u16 h){ return __uint_as_float(((u32)h) << 16); }

// map (chunk, local col) -> global node index in reference W order, or -1 (zero pad)
__device__ __forceinline__ int nodemap(int ch, int n){
  if (ch == 0) return (n < 15) ? n : -1;            // prefix: global nodes 0..14
  if (n >= 63) return -1;
  int v = n + 1;
  int L = 31 - __clz(v);                            // local level 0..5  (tree depth L+4)
  return ((1 << (L + 4)) - 1) + ((ch - 1) << L) + (v - (1 << L));
}

// =====================  prep: pack W/Q fragments + (-beta, -beta*b) table  =====================
__global__ void sdt_prep(const float* __restrict__ W, const float* __restrict__ b,
                         const float* __restrict__ beta, const float* __restrict__ LP,
                         char* __restrict__ ws)
{
  const int bid = blockIdx.x, t = threadIdx.x;
  u16* wfrag = (u16*)(ws + WS_WFRAG);
  u16* qfrag = (u16*)(ws + WS_QFRAG);
  float2* eb = (float2*)(ws + WS_EBTAB);

  if (bid < 34){                                    // W fragments: [17][4][2][64] threads
    int id = bid*256 + t;
    if (id < 17*4*2*64){
      int lane = id & 63, kt = (id >> 6) & 1, ct = (id >> 7) & 3, ch = id >> 9;
      int n = ct*16 + (lane & 15);
      int g = nodemap(ch, n);
      int k0 = kt*32 + ((lane >> 4) << 3);
      size_t basH = ((((size_t)ch*4 + ct)*2 + kt)*2 + 0)*512 + (size_t)lane*8;
      size_t basL = basH + 512;
      #pragma unroll
      for (int j = 0; j < 8; ++j){
        float v = (g >= 0) ? W[(size_t)g*64 + k0 + j] : 0.0f;
        u16 h = f2bf(v);
        wfrag[basH + j] = h;
        wfrag[basL + j] = f2bf(v - bf2f(h));
      }
    }
  } else if (bid < 42){                             // Q fragments: [16][2][64] threads
    int id = (bid - 34)*256 + t;
    int lane = id & 63, kt = (id >> 6) & 1, s = id >> 7;
    int c = lane & 15;
    size_t basH = (((size_t)s*2 + kt)*2 + 0)*512 + (size_t)lane*8;
    size_t basL = basH + 512;
    #pragma unroll
    for (int j = 0; j < 8; ++j){
      int leaf = s*64 + kt*32 + ((lane >> 4) << 3) + j;
      const float* row = LP + (size_t)leaf*16;
      float m = row[0];
      #pragma unroll
      for (int cc = 1; cc < 16; ++cc) m = fmaxf(m, row[cc]);
      float ssum = 0.f;
      #pragma unroll
      for (int cc = 0; cc < 16; ++cc) ssum += __expf(row[cc] - m);
      float q = __expf(row[c] - m) / ssum;
      u16 h = f2bf(q);
      qfrag[basH + j] = h;
      qfrag[basL + j] = f2bf(q - bf2f(h));
    }
  } else {                                          // folded sigmoid tables
    int id = (bid - 42)*256 + t;
    if (id < 17*64){
      int n = id & 63, ch = id >> 6;
      int g = nodemap(ch, n);
      float be = (g >= 0) ? beta[g] : 0.0f;
      float bb = (g >= 0) ? b[g]    : 0.0f;
      eb[id] = make_float2(-be, -be * bb);
    }
  }
}

// =====================  main fused kernel  =====================
// grid 2048 x 256 threads; block handles 64 rows; wave w owns rows w*16..w*16+15.
// After the 2 prologue barriers everything is wave-private: NO barriers in main loop.
__global__ __launch_bounds__(256, 3) void sdt_main(
    const float* __restrict__ X, const char* __restrict__ ws,
    float* __restrict__ out)
{
  __shared__ float sP[4][16*67];      // per-wave sigmoid slice, stride 67 (bank-clean)  16.75 KB
  __shared__ float sPath[4][16*17];   // per-wave level-4 prefix probs                    4.25 KB
  __shared__ char  sLp[4][4096];      // per-wave leaf-path frags (A-frag-major layout)  16 KB
                                      // prologue: sLp doubles as the X staging buffer (hi 8K | lo 8K)

  const int tid  = threadIdx.x;
  const int w    = tid >> 6;
  const int lane = tid & 63;
  const int bid  = blockIdx.x;

  const u16*    wfrag = (const u16*)(ws + WS_WFRAG);
  const u16*    qfrag = (const u16*)(ws + WS_QFRAG);
  const float2* ebTab = (const float2*)(ws + WS_EBTAB);

  // ---- prologue: stage X tile (64x64 fp32 -> bf16 hi/lo, swizzled) into sLp region ----
  char* sX = (char*)sLp;     // hi at [0,8192), lo at [8192,16384)
  {
    const float4* Xg = (const float4*)X + (size_t)bid * 1024;
    #pragma unroll
    for (int i = 0; i < 4; ++i){
      int f = tid + i*256;
      float4 v = Xg[f];
      int row = f >> 4;
      int byteo = row*128 + (f & 15)*8;
      int swz = (row & 7) << 4;
      u16 h0 = f2bf(v.x), h1 = f2bf(v.y), h2 = f2bf(v.z), h3 = f2bf(v.w);
      bf16x4 hv = {(short)h0, (short)h1, (short)h2, (short)h3};
      bf16x4 lv = {(short)f2bf(v.x - bf2f(h0)), (short)f2bf(v.y - bf2f(h1)),
                   (short)f2bf(v.z - bf2f(h2)), (short)f2bf(v.w - bf2f(h3))};
      *(bf16x4*)(sX + (byteo ^ swz)) = hv;
      *(bf16x4*)(sX + 8192 + (byteo ^ swz)) = lv;
    }
  }
  __syncthreads();

  // persistent X A-fragments for this wave's 16 rows (k-invariant across chunks)
  const int mA   = lane & 15;
  const int kofs = (lane >> 4) * 16;          // byte offset of 8-element k-block
  const int swzA = (mA & 7) << 4;
  const int rowb = (w*16 + mA) * 128;
  const bf16x8 aH0 = *(const bf16x8*)(sX + ((rowb + kofs     ) ^ swzA));
  const bf16x8 aH1 = *(const bf16x8*)(sX + ((rowb + 64 + kofs) ^ swzA));
  const bf16x8 aL0 = *(const bf16x8*)(sX + 8192 + ((rowb + kofs     ) ^ swzA));
  const bf16x8 aL1 = *(const bf16x8*)(sX + 8192 + ((rowb + 64 + kofs) ^ swzA));
  __syncthreads();                            // all waves done with X region -> becomes Lp space

  f32x4 accO = {0.f, 0.f, 0.f, 0.f};          // out tile [16 rows][16 ch], accumulated over chunks
  const int mrow = lane >> 2;                 // 0..15 mixing row
  const int q4   = lane & 3;                  // leaf quarter (16 leaves each)
  float* Pw    = sP[w];
  float* pathw = sPath[w];
  u16*   lpW   = (u16*)sLp[w];                // [hi mf0 1K | hi mf1 1K | lo mf0 1K | lo mf1 1K]

  for (int ch = 0; ch < NCH; ++ch){
    // ---- Q fragments for this chunk's mixing (direct from L1/L2, issued early) ----
    const int s = (ch >= 1) ? (ch - 1) : 0;
    const u16* qb = qfrag + (size_t)s * 2048;
    const bf16x8 qH0 = *(const bf16x8*)(qb +    0 + lane*8);
    const bf16x8 qL0 = *(const bf16x8*)(qb +  512 + lane*8);
    const bf16x8 qH1 = *(const bf16x8*)(qb + 1024 + lane*8);
    const bf16x8 qL1 = *(const bf16x8*)(qb + 1536 + lane*8);

    // ---- z = X@W'^T (split bf16, 3 products) ; p = 1/(1+exp(-beta(z+b))) -> sP ----
    const int ncts = (ch == 0) ? 1 : 4;
    const u16* wb = wfrag + (size_t)ch * 8192;
    for (int ct = 0; ct < ncts; ++ct){
      const u16* wc = wb + ct*2048;
      const bf16x8 wH0 = *(const bf16x8*)(wc +    0 + lane*8);
      const bf16x8 wL0 = *(const bf16x8*)(wc +  512 + lane*8);
      const bf16x8 wH1 = *(const bf16x8*)(wc + 1024 + lane*8);
      const bf16x8 wL1 = *(const bf16x8*)(wc + 1536 + lane*8);
      f32x4 az = {0.f, 0.f, 0.f, 0.f};
      az = MFMA(aH0, wH0, az);
      az = MFMA(aH1, wH1, az);
      az = MFMA(aH0, wL0, az);
      az = MFMA(aH1, wL1, az);
      az = MFMA(aL0, wH0, az);
      az = MFMA(aL1, wH1, az);
      const int n = ct*16 + (lane & 15);
      const float2 eb = ebTab[ch*64 + n];
      #pragma unroll
      for (int r = 0; r < 4; ++r){
        const int m = (lane >> 4)*4 + r;
        const float u = __expf(fmaf(az[r], eb.x, eb.y));
        Pw[m*67 + n] = __builtin_amdgcn_rcpf(1.0f + u);
      }
    }

    // ---- per-sample tree mixing (wave-private LDS; barrier-free) ----
    if (ch == 0){
      // prefix path to the 16 level-4 subtrees
      #pragma unroll
      for (int u = 0; u < 4; ++u){
        const int t = q4*4 + u;
        const float* Pr = &Pw[mrow*67];
        float p0 = Pr[0], p1 = Pr[1 + (t>>3)], p2 = Pr[3 + (t>>2)], p3 = Pr[7 + (t>>1)];
        float f0 = (t & 8) ? p0 : 1.f - p0;
        float f1 = (t & 4) ? p1 : 1.f - p1;
        float f2 = (t & 2) ? p2 : 1.f - p2;
        float f3 = (t & 1) ? p3 : 1.f - p3;
        pathw[mrow*17 + t] = f0*f1*f2*f3;
      }
    } else {
      const float pf = pathw[mrow*17 + s];
      const float* Pr = &Pw[mrow*67];
      const float pA = Pr[0];
      const float pB = Pr[1 + (q4 >> 1)];
      const float pC = Pr[3 + q4];
      const float lpre = pf * ((q4 & 2) ? pA : 1.f - pA) * ((q4 & 1) ? pB : 1.f - pB);
      float a2[2], a3[4], a4[8], a5[16];
      a2[0] = lpre * (1.f - pC); a2[1] = lpre * pC;
      #pragma unroll
      for (int i = 0; i < 2; ++i){
        float p = Pr[7 + 2*q4 + i];
        a3[2*i] = a2[i]*(1.f - p); a3[2*i+1] = a2[i]*p;
      }
      #pragma unroll
      for (int i = 0; i < 4; ++i){
        float p = Pr[15 + 4*q4 + i];
        a4[2*i] = a3[i]*(1.f - p); a4[2*i+1] = a3[i]*p;
      }
      #pragma unroll
      for (int i = 0; i < 8; ++i){
        float p = Pr[31 + 8*q4 + i];
        a5[2*i] = a4[i]*(1.f - p); a5[2*i+1] = a4[i]*p;
      }
      // truncation split to bf16 hi/lo, packed pairwise with v_perm
      u32 hiw[8], low[8];
      #pragma unroll
      for (int i = 0; i < 8; ++i){
        u32 u0 = __float_as_uint(a5[2*i]);
        u32 u1 = __float_as_uint(a5[2*i+1]);
        hiw[i] = __builtin_amdgcn_perm(u1, u0, 0x07060302u);
        float l0 = a5[2*i]   - __uint_as_float(u0 & 0xffff0000u);
        float l1 = a5[2*i+1] - __uint_as_float(u1 & 0xffff0000u);
        low[i] = __builtin_amdgcn_perm(__float_as_uint(l1), __float_as_uint(l0), 0x07060302u);
      }
      // store A-frag-major: writer (mrow,q4) -> mf = q4>>1, hi-slots 2*(q4&1), 2*(q4&1)+1
      {
        char* dh = (char*)lpW + (q4 >> 1)*1024 + (((q4 & 1)*2)*16 + mrow)*16;
        *(u32x4*)(dh       ) = u32x4{hiw[0], hiw[1], hiw[2], hiw[3]};
        *(u32x4*)(dh + 256 ) = u32x4{hiw[4], hiw[5], hiw[6], hiw[7]};
        *(u32x4*)(dh + 2048) = u32x4{low[0], low[1], low[2], low[3]};
        *(u32x4*)(dh + 2304) = u32x4{low[4], low[5], low[6], low[7]};
      }
      // read back as MFMA A fragments: lane-contiguous, conflict-free
      const char* lb = (const char*)lpW + lane*16;
      const bf16x8 pH0 = *(const bf16x8*)(lb       );
      const bf16x8 pH1 = *(const bf16x8*)(lb + 1024);
      const bf16x8 pL0 = *(const bf16x8*)(lb + 2048);
      const bf16x8 pL1 = *(const bf16x8*)(lb + 3072);
      // out += lp @ Q_s   (3-product split: lpH*Qh, lpL*Qh, lpH*Ql)
      accO = MFMA(pH0, qH0, accO);
      accO = MFMA(pH1, qH1, accO);
      accO = MFMA(pL0, qH0, accO);
      accO = MFMA(pL1, qH1, accO);
      accO = MFMA(pH0, qL0, accO);
      accO = MFMA(pH1, qL1, accO);
    }
  }

  // ---- epilogue: rows bid*64 + w*16 + m, cols lane&15 ----
  const size_t ob = ((size_t)bid*64 + w*16) * 16 + (lane & 15);
  #pragma unroll
  for (int r = 0; r < 4; ++r){
    const int m = (lane >> 4)*4 + r;
    out[ob + (size_t)m*16] = accO[r];
  }
}

extern "C" void kernel_launch(void* const* d_in, const int* in_sizes, int n_in,
                              void* d_out, int out_size, void* d_ws, size_t ws_size,
                              hipStream_t stream)
{
  const float* X    = (const float*)d_in[0];
  const float* W    = (const float*)d_in[1];
  const float* b    = (const float*)d_in[2];
  const float* beta = (const float*)d_in[3];
  const float* LP   = (const float*)d_in[4];
  float* out = (float*)d_out;
  char*  ws  = (char*)d_ws;

  if (ws_size < WS_NEED) return;   // leaves d_out poisoned -> loud failure instead of UB

  sdt_prep<<<47, 256, 0, stream>>>(W, b, beta, LP, ws);
  sdt_main<<<2048, 256, 0, stream>>>(X, ws, out);
}